// Round 1
// baseline (444.431 us; speedup 1.0000x reference)
//
#include <hip/hip_runtime.h>

// DepthToSpace DCR, block_size=2.
// in:  (16, 256, 128, 128) f32
// out: (16,  64, 256, 256) f32
// out[b, c, 2h+j, 2w+r] = in[b, (2j+r)*64 + c, h, w]
//
// v2: each thread handles BOTH output rows (j=0,1) of one (b,c,h,w4) cell:
//   - 4 independent nontemporal float4 loads (channels c, c+64, c+128, c+192)
//   - 4 nontemporal float4 stores (2 per output row, interleaved r=0/r=1)
// Halves thread count vs v1, doubles load ILP, and bypasses L2/L3 pollution
// (512 MiB streamed once > 256 MiB L3). All accesses fully coalesced:
// per half-wave, reads are 512B contiguous per stream, writes cover complete
// 1024B output rows (whole cache lines).

constexpr int B  = 16;
constexpr int D  = 256;
constexpr int H  = 128;
constexpr int W  = 128;
constexpr int BS = 2;
constexpr int C  = D / (BS * BS);   // 64
constexpr int H2 = H * BS;          // 256
constexpr int W2 = W * BS;          // 256

typedef float f4 __attribute__((ext_vector_type(4)));

__global__ __launch_bounds__(256) void d2s_kernel(const float* __restrict__ in,
                                                  float* __restrict__ out) {
    const int tid = blockIdx.x * blockDim.x + threadIdx.x;
    // thread layout: [b][c][h][w4], w4 in [0,32) selecting 4 input w's
    const int w4    = tid & 31;          // W/4 = 32 groups per input row
    const int rest  = tid >> 5;
    const int h     = rest & (H - 1);    // 128
    const int rest2 = rest >> 7;
    const int c     = rest2 & (C - 1);   // 64
    const int b     = rest2 >> 6;

    // float4-granular indices (all buffers 16B aligned, W % 4 == 0)
    const size_t in_base = ((size_t)((b * D + c) * H + h) * W) >> 2; // k=0 stream
    constexpr size_t CH4 = (size_t)C * H * W / 4;                    // 262144: one C-group

    const f4* __restrict__ ip = reinterpret_cast<const f4*>(in);
    const f4 a0 = __builtin_nontemporal_load(ip + in_base + 0 * CH4 + w4); // ch c       (j=0,r=0)
    const f4 a1 = __builtin_nontemporal_load(ip + in_base + 1 * CH4 + w4); // ch c+64    (j=0,r=1)
    const f4 a2 = __builtin_nontemporal_load(ip + in_base + 2 * CH4 + w4); // ch c+128   (j=1,r=0)
    const f4 a3 = __builtin_nontemporal_load(ip + in_base + 3 * CH4 + w4); // ch c+192   (j=1,r=1)

    const size_t out_row0 = (((size_t)((b * C + c) * H2 + 2 * h)) * W2) >> 2; // float4 units
    f4* __restrict__ op = reinterpret_cast<f4*>(out);
    f4* o0 = op + out_row0 + (w4 << 1);   // row ho = 2h
    f4* o1 = o0 + (W2 >> 2);              // row ho = 2h+1 (stride 64 float4s)

    const f4 r0 = {a0.x, a1.x, a0.y, a1.y};
    const f4 r1 = {a0.z, a1.z, a0.w, a1.w};
    const f4 r2 = {a2.x, a3.x, a2.y, a3.y};
    const f4 r3 = {a2.z, a3.z, a2.w, a3.w};

    __builtin_nontemporal_store(r0, o0 + 0);
    __builtin_nontemporal_store(r1, o0 + 1);
    __builtin_nontemporal_store(r2, o1 + 0);
    __builtin_nontemporal_store(r3, o1 + 1);
}

extern "C" void kernel_launch(void* const* d_in, const int* in_sizes, int n_in,
                              void* d_out, int out_size, void* d_ws, size_t ws_size,
                              hipStream_t stream) {
    const float* in = (const float*)d_in[0];
    float* out = (float*)d_out;

    // total threads = B*C*H*(W/4) = 16*64*128*32 = 4,194,304
    const int total_threads = B * C * H * (W / 4);
    const int block = 256;
    const int grid = total_threads / block;   // 16384

    d2s_kernel<<<grid, block, 0, stream>>>(in, out);
}

// Round 2
// 426.459 us; speedup vs baseline: 1.0421x; 1.0421x over previous
//
#include <hip/hip_runtime.h>

// DepthToSpace DCR, block_size=2.
// in:  (16, 256, 128, 128) f32
// out: (16,  64, 256, 256) f32
// out[b, c, 2h+j, 2w+r] = in[b, (2j+r)*64 + c, h, w]
//
// v3: output-centric, every memory instruction wave-contiguous.
//  - thread owns (b, c, h, wq), wq in [0,64): one float4 output group in each
//    of the two output rows 2h and 2h+1.
//  - 4 float2 loads (8B/lane; wave = 512B contiguous per channel stream)
//  - 2 float4 stores (16B/lane; wave = one full 1KiB output row, contiguous)
//  - regular cached accesses: input (~268MB) is L3-resident across iterations,
//    stores merge to full lines in L2. (v2's nontemporal hints regressed:
//    NT loads forfeited L3 hits, NT 16B@32B-stride stores made partial lines.)

constexpr int B  = 16;
constexpr int D  = 256;
constexpr int H  = 128;
constexpr int W  = 128;
constexpr int BS = 2;
constexpr int C  = D / (BS * BS);   // 64
constexpr int H2 = H * BS;          // 256
constexpr int W2 = W * BS;          // 256

typedef float f2 __attribute__((ext_vector_type(2)));
typedef float f4 __attribute__((ext_vector_type(4)));

__global__ __launch_bounds__(256) void d2s_kernel(const float* __restrict__ in,
                                                  float* __restrict__ out) {
    const int tid = blockIdx.x * blockDim.x + threadIdx.x;
    // thread layout: [b][c][h][wq], wq in [0,64) = W2/4 output float4 groups
    const int wq = tid & 63;
    const int h  = (tid >> 6) & (H - 1);    // 128
    const int c  = (tid >> 13) & (C - 1);   // 64
    const int b  = tid >> 19;

    // input float2 index for stream k: ((b*D + k*C + c)*H + h) * (W/2) + wq
    const size_t in_base = ((size_t)((b * D + c) * H + h)) * (W / 2) + wq;
    constexpr size_t CH2 = (size_t)C * H * W / 2;   // one channel-group in f2 units

    const f2* __restrict__ ip = reinterpret_cast<const f2*>(in);
    const f2 p0 = ip[in_base + 0 * CH2];   // k0 = c        (j=0, r=0)
    const f2 p1 = ip[in_base + 1 * CH2];   // k1 = C + c    (j=0, r=1)
    const f2 p2 = ip[in_base + 2 * CH2];   // k2 = 2C + c   (j=1, r=0)
    const f2 p3 = ip[in_base + 3 * CH2];   // k3 = 3C + c   (j=1, r=1)

    // output rows 2h (j=0) and 2h+1 (j=1); each row = W2/4 = 64 float4s
    const size_t out_row0 = ((size_t)((b * C + c) * H2 + 2 * h)) * (W2 / 4) + wq;
    f4* __restrict__ op = reinterpret_cast<f4*>(out);

    op[out_row0]            = f4{p0.x, p1.x, p0.y, p1.y};   // row 2h
    op[out_row0 + (W2 / 4)] = f4{p2.x, p3.x, p2.y, p3.y};   // row 2h+1
}

extern "C" void kernel_launch(void* const* d_in, const int* in_sizes, int n_in,
                              void* d_out, int out_size, void* d_ws, size_t ws_size,
                              hipStream_t stream) {
    const float* in = (const float*)d_in[0];
    float* out = (float*)d_out;

    // total threads = B*C*H*(W2/4) = 16*64*128*64 = 8,388,608
    const int total_threads = B * C * H * (W2 / 4);
    const int block = 256;
    const int grid = total_threads / block;   // 32768

    d2s_kernel<<<grid, block, 0, stream>>>(in, out);
}